// Round 1
// baseline (758.161 us; speedup 1.0000x reference)
//
#include <hip/hip_runtime.h>
#include <hip/hip_bf16.h>
#include <math.h>

#define NB    64          // number of segments (B)
#define CD    512         // channels C
#define CV    128         // C / 4 (float4 per row)
#define MIDD  2048        // 4*C
#define RS    32          // row-splits per segment in pass 1
#define EPSV  1e-5f

// ---------------- Pass 1: per-segment partial sums ----------------
// grid = NB*RS blocks, 128 threads (thread = float4 column)
__global__ void k_partial(const float* __restrict__ x2,
                          const int* __restrict__ npoint,
                          float* __restrict__ P) {
    int bx = blockIdx.x;
    int b  = bx >> 5;            // / RS
    int rs = bx & (RS - 1);
    int start = 0;
    for (int i = 0; i < b; ++i) start += npoint[i];
    int len   = npoint[b];
    int chunk = (len + RS - 1) / RS;
    int r0 = rs * chunk;
    int r1 = min(r0 + chunk, len);
    int t = threadIdx.x;
    const float4* xv = (const float4*)x2;
    float4 acc = make_float4(0.f, 0.f, 0.f, 0.f);
    #pragma unroll 4
    for (int r = r0; r < r1; ++r) {
        float4 v = xv[(size_t)(start + r) * CV + t];
        acc.x += v.x; acc.y += v.y; acc.z += v.z; acc.w += v.w;
    }
    ((float4*)P)[(size_t)bx * CV + t] = acc;
}

// ---------------- Pass 1b: reduce partials -> mean_f, compute cum ----------------
// grid = NB blocks, 128 threads
__global__ void k_mean(const float* __restrict__ P,
                       const int* __restrict__ npoint,
                       float* __restrict__ mean_f,
                       int* __restrict__ cum) {
    int b = blockIdx.x;
    int t = threadIdx.x;
    const float4* Pv = (const float4*)P;
    float4 acc = make_float4(0.f, 0.f, 0.f, 0.f);
    #pragma unroll
    for (int rs = 0; rs < RS; ++rs) {
        float4 v = Pv[((size_t)(b * RS + rs)) * CV + t];
        acc.x += v.x; acc.y += v.y; acc.z += v.z; acc.w += v.w;
    }
    float inv = 1.0f / (float)npoint[b];
    acc.x *= inv; acc.y *= inv; acc.z *= inv; acc.w *= inv;
    ((float4*)mean_f)[(size_t)b * CV + t] = acc;
    if (t == 0) {
        int s = 0;
        for (int i = 0; i <= b; ++i) s += npoint[i];
        cum[b] = s;
    }
}

__device__ __forceinline__ float wave_sum64(float x) {
    #pragma unroll
    for (int o = 32; o; o >>= 1) x += __shfl_xor(x, o, 64);
    return x;
}

// ---------------- FC1 + BN + ReLU (both branches) ----------------
// grid = 2 * (MIDD/8) = 512 blocks, 64 threads (thread = batch row)
__global__ __launch_bounds__(64) void k_fc1(const float* __restrict__ mean_f,
                                            const float* __restrict__ W1a,
                                            const float* __restrict__ g1a,
                                            const float* __restrict__ b1a,
                                            const float* __restrict__ W1b,
                                            const float* __restrict__ g1b,
                                            const float* __restrict__ b1b,
                                            float* __restrict__ h) {
    int bx = blockIdx.x;
    int branch = bx >> 8;            // 256 groups per branch
    int cg = bx & 255;
    int c0 = cg * 8;
    const float* W1 = branch ? W1b : W1a;
    const float* g  = branch ? g1b : g1a;
    const float* bb = branch ? b1b : b1a;
    int t = threadIdx.x;             // row 0..63
    const float4* mrow = (const float4*)(mean_f + (size_t)t * CD);
    float acc[8];
    #pragma unroll
    for (int i = 0; i < 8; ++i) acc[i] = 0.f;
    for (int k = 0; k < CD; k += 8) {
        float4 m0 = mrow[k >> 2];
        float4 m1 = mrow[(k >> 2) + 1];
        float mf[8] = {m0.x, m0.y, m0.z, m0.w, m1.x, m1.y, m1.z, m1.w};
        #pragma unroll
        for (int j = 0; j < 8; ++j) {
            const float* wrow = W1 + (size_t)(k + j) * MIDD + c0;
            #pragma unroll
            for (int i = 0; i < 8; ++i) acc[i] += mf[j] * wrow[i];
        }
    }
    #pragma unroll
    for (int i = 0; i < 8; ++i) {
        float s = wave_sum64(acc[i]);
        float m = s * (1.0f / 64.0f);
        float d = acc[i] - m;
        float q = wave_sum64(d * d);
        float v = q * (1.0f / 64.0f);
        float val = d * rsqrtf(v + EPSV) * g[c0 + i] + bb[c0 + i];
        val = fmaxf(val, 0.0f);
        h[((size_t)branch * NB + t) * MIDD + c0 + i] = val;
    }
}

// ---------------- FC2 (+ReLU, +sigmoid for branch b) ----------------
// grid = 2 * (CD/8) = 128 blocks, 64 threads
__global__ __launch_bounds__(64) void k_fc2(const float* __restrict__ h,
                                            const float* __restrict__ W2a,
                                            const float* __restrict__ W2b,
                                            float* __restrict__ out_mean,
                                            float* __restrict__ out_w) {
    int bx = blockIdx.x;
    int branch = bx >> 6;            // 64 groups per branch
    int cg = bx & 63;
    int c0 = cg * 8;
    const float* W2 = branch ? W2b : W2a;
    int t = threadIdx.x;
    const float4* hrow = (const float4*)(h + ((size_t)branch * NB + t) * MIDD);
    float acc[8];
    #pragma unroll
    for (int i = 0; i < 8; ++i) acc[i] = 0.f;
    for (int k = 0; k < MIDD; k += 8) {
        float4 h0 = hrow[k >> 2];
        float4 h1 = hrow[(k >> 2) + 1];
        float hf[8] = {h0.x, h0.y, h0.z, h0.w, h1.x, h1.y, h1.z, h1.w};
        #pragma unroll
        for (int j = 0; j < 8; ++j) {
            const float* wrow = W2 + (size_t)(k + j) * CD + c0;
            #pragma unroll
            for (int i = 0; i < 8; ++i) acc[i] += hf[j] * wrow[i];
        }
    }
    if (branch == 0) {
        #pragma unroll
        for (int i = 0; i < 8; ++i)
            out_mean[(size_t)t * CD + c0 + i] = fmaxf(acc[i], 0.0f);
    } else {
        #pragma unroll
        for (int i = 0; i < 8; ++i) {
            float r = fmaxf(acc[i], 0.0f);
            out_w[(size_t)t * CD + c0 + i] = 1.0f / (1.0f + expf(-r));
        }
    }
}

// ---------------- Final combine ----------------
// one float4 per thread; grid = N*C/4/256 blocks, 256 threads
__global__ void k_final(const float* __restrict__ x2,
                        const int* __restrict__ cum,
                        const float* __restrict__ out_mean,
                        const float* __restrict__ out_w,
                        float* __restrict__ out) {
    size_t gid = (size_t)blockIdx.x * 256 + threadIdx.x;   // float4 index
    int row  = (int)(gid >> 7);       // / (C/4)
    int colv = (int)(gid & 127);
    // seg = first i with cum[i] > row  (searchsorted right)
    int lo = 0, hi = NB - 1;
    while (lo < hi) {
        int mid = (lo + hi) >> 1;
        if (cum[mid] > row) hi = mid; else lo = mid + 1;
    }
    int seg = lo;
    float4 x = ((const float4*)x2)[gid];
    float4 w = ((const float4*)out_w)[(size_t)seg * CV + colv];
    float4 m = ((const float4*)out_mean)[(size_t)seg * CV + colv];
    float4 o;
    o.x = x.x * (0.5f * w.x + 0.75f) + m.x;
    o.y = x.y * (0.5f * w.y + 0.75f) + m.y;
    o.z = x.z * (0.5f * w.z + 0.75f) + m.z;
    o.w = x.w * (0.5f * w.w + 0.75f) + m.w;
    ((float4*)out)[gid] = o;
}

extern "C" void kernel_launch(void* const* d_in, const int* in_sizes, int n_in,
                              void* d_out, int out_size, void* d_ws, size_t ws_size,
                              hipStream_t stream) {
    const float* x2  = (const float*)d_in[0];
    const int*   npt = (const int*)d_in[1];
    const float* W1a = (const float*)d_in[2];
    const float* g1a = (const float*)d_in[3];
    const float* b1a = (const float*)d_in[4];
    const float* W2a = (const float*)d_in[5];
    const float* W1b = (const float*)d_in[6];
    const float* g1b = (const float*)d_in[7];
    const float* b1b = (const float*)d_in[8];
    const float* W2b = (const float*)d_in[9];
    float* out = (float*)d_out;

    const int N  = in_sizes[0] / CD;      // 262144
    const int NC4 = (N * CD) / 4;         // float4 count

    // scratch: big dead-before-final arrays live in d_out
    float* P      = out;                              // [NB*RS*CD]  = 4 MB
    float* mean_f = out + (size_t)NB * RS * CD;       // [NB*CD]     = 128 KB
    float* h      = mean_f + (size_t)NB * CD;         // [2*NB*MIDD] = 1 MB
    // small live-at-final arrays in ws
    int*   cum      = (int*)d_ws;                     // 64 ints
    float* out_mean = (float*)d_ws + 64;              // [NB*CD]
    float* out_w    = out_mean + (size_t)NB * CD;     // [NB*CD]

    k_partial<<<NB * RS, 128, 0, stream>>>(x2, npt, P);
    k_mean<<<NB, 128, 0, stream>>>(P, npt, mean_f, cum);
    k_fc1<<<2 * (MIDD / 8), 64, 0, stream>>>(mean_f, W1a, g1a, b1a, W1b, g1b, b1b, h);
    k_fc2<<<2 * (CD / 8), 64, 0, stream>>>(h, W2a, W2b, out_mean, out_w);
    k_final<<<NC4 / 256, 256, 0, stream>>>(x2, cum, out_mean, out_w, out);
}

// Round 2
// 374.284 us; speedup vs baseline: 2.0256x; 2.0256x over previous
//
#include <hip/hip_runtime.h>
#include <hip/hip_bf16.h>
#include <math.h>

#define NB    64          // number of segments (B)
#define CD    512         // channels C
#define CV    128         // C / 4 (float4 per row)
#define MIDD  2048        // 4*C
#define RS    32          // row-splits per segment in pass 1
#define EPSV  1e-5f

__device__ __forceinline__ float wave_sum64(float x) {
    #pragma unroll
    for (int o = 32; o; o >>= 1) x += __shfl_xor(x, o, 64);
    return x;
}

// ---------------- Pass 1: per-segment partial sums ----------------
// grid = NB*RS blocks, 128 threads (thread = float4 column)
__global__ __launch_bounds__(128) void k_partial(const float* __restrict__ x2,
                          const int* __restrict__ npoint,
                          float* __restrict__ P) {
    int bx = blockIdx.x;
    int b  = bx >> 5;            // / RS
    int rs = bx & (RS - 1);
    int start = 0;
    for (int i = 0; i < b; ++i) start += npoint[i];
    int len   = npoint[b];
    int chunk = (len + RS - 1) / RS;
    int r0 = rs * chunk;
    int r1 = min(r0 + chunk, len);
    int t = threadIdx.x;
    const float4* xv = (const float4*)x2;
    float4 acc = make_float4(0.f, 0.f, 0.f, 0.f);
    #pragma unroll 8
    for (int r = r0; r < r1; ++r) {
        float4 v = xv[(size_t)(start + r) * CV + t];
        acc.x += v.x; acc.y += v.y; acc.z += v.z; acc.w += v.w;
    }
    ((float4*)P)[(size_t)bx * CV + t] = acc;
}

// ---------------- Pass 1b: reduce partials -> mean_t (transposed [C][NB]), cum ----------------
// grid = NB blocks, 128 threads
__global__ __launch_bounds__(128) void k_mean(const float* __restrict__ P,
                       const int* __restrict__ npoint,
                       float* __restrict__ mean_t,
                       int* __restrict__ cum) {
    int b = blockIdx.x;
    int t = threadIdx.x;
    const float4* Pv = (const float4*)P;
    float4 acc = make_float4(0.f, 0.f, 0.f, 0.f);
    #pragma unroll
    for (int rs = 0; rs < RS; ++rs) {
        float4 v = Pv[((size_t)(b * RS + rs)) * CV + t];
        acc.x += v.x; acc.y += v.y; acc.z += v.z; acc.w += v.w;
    }
    float inv = 1.0f / (float)npoint[b];
    int c = 4 * t;
    mean_t[(size_t)(c + 0) * NB + b] = acc.x * inv;
    mean_t[(size_t)(c + 1) * NB + b] = acc.y * inv;
    mean_t[(size_t)(c + 2) * NB + b] = acc.z * inv;
    mean_t[(size_t)(c + 3) * NB + b] = acc.w * inv;
    if (t == 0) {
        int s = 0;
        for (int i = 0; i <= b; ++i) s += npoint[i];
        cum[b] = s;
    }
}

// ---------------- FC1 + BN + ReLU (both branches), 8-way K-split ----------------
// grid = 2 * (MIDD/8) = 512 blocks, 512 threads (8 waves; lane = batch row)
__global__ __launch_bounds__(512) void k_fc1(const float* __restrict__ mean_t,
                                             const float* __restrict__ W1a,
                                             const float* __restrict__ g1a,
                                             const float* __restrict__ b1a,
                                             const float* __restrict__ W1b,
                                             const float* __restrict__ g1b,
                                             const float* __restrict__ b1b,
                                             float* __restrict__ h_t) {
    __shared__ float red[8][64][9];
    int bx = blockIdx.x;
    int branch = bx >> 8;            // 256 col-groups per branch
    int cg = bx & 255;
    int c0 = cg * 8;
    const float* W1 = branch ? W1b : W1a;
    const float* g  = branch ? g1b : g1a;
    const float* bb = branch ? b1b : b1a;
    int t = threadIdx.x;
    int lane = t & 63;               // batch row
    int w = t >> 6;                  // wave id = K-chunk = epilogue column
    float acc[8];
    #pragma unroll
    for (int i = 0; i < 8; ++i) acc[i] = 0.f;
    int k0 = w * 64;
    for (int k = k0; k < k0 + 64; ++k) {
        float mval = mean_t[(size_t)k * NB + lane];           // coalesced
        const float4* wr = (const float4*)(W1 + (size_t)k * MIDD + c0);
        float4 w0 = wr[0], w1 = wr[1];                        // broadcast
        acc[0] += mval * w0.x; acc[1] += mval * w0.y;
        acc[2] += mval * w0.z; acc[3] += mval * w0.w;
        acc[4] += mval * w1.x; acc[5] += mval * w1.y;
        acc[6] += mval * w1.z; acc[7] += mval * w1.w;
    }
    #pragma unroll
    for (int i = 0; i < 8; ++i) red[w][lane][i] = acc[i];
    __syncthreads();
    // epilogue: wave w owns column c0+w
    float v = red[0][lane][w];
    #pragma unroll
    for (int ww = 1; ww < 8; ++ww) v += red[ww][lane][w];
    float s = wave_sum64(v);
    float m = s * (1.0f / 64.0f);
    float d = v - m;
    float q = wave_sum64(d * d);
    float var = q * (1.0f / 64.0f);
    float val = fmaxf(d * rsqrtf(var + EPSV) * g[c0 + w] + bb[c0 + w], 0.0f);
    h_t[((size_t)branch * MIDD + c0 + w) * NB + lane] = val;  // coalesced
}

// ---------------- FC2 (+ReLU, +sigmoid for branch b), 8-way K-split ----------------
// grid = 2 * (CD/8) = 128 blocks, 512 threads
__global__ __launch_bounds__(512) void k_fc2(const float* __restrict__ h_t,
                                             const float* __restrict__ W2a,
                                             const float* __restrict__ W2b,
                                             float* __restrict__ out_mean,
                                             float* __restrict__ out_w) {
    __shared__ float red[8][64][9];
    int bx = blockIdx.x;
    int branch = bx >> 6;            // 64 col-groups per branch
    int cg = bx & 63;
    int c0 = cg * 8;
    const float* W2 = branch ? W2b : W2a;
    int t = threadIdx.x;
    int lane = t & 63;
    int w = t >> 6;
    float acc[8];
    #pragma unroll
    for (int i = 0; i < 8; ++i) acc[i] = 0.f;
    int k0 = w * 256;
    for (int k = k0; k < k0 + 256; ++k) {
        float hv = h_t[((size_t)branch * MIDD + k) * NB + lane];   // coalesced
        const float4* wr = (const float4*)(W2 + (size_t)k * CD + c0);
        float4 w0 = wr[0], w1 = wr[1];                             // broadcast
        acc[0] += hv * w0.x; acc[1] += hv * w0.y;
        acc[2] += hv * w0.z; acc[3] += hv * w0.w;
        acc[4] += hv * w1.x; acc[5] += hv * w1.y;
        acc[6] += hv * w1.z; acc[7] += hv * w1.w;
    }
    #pragma unroll
    for (int i = 0; i < 8; ++i) red[w][lane][i] = acc[i];
    __syncthreads();
    float v = red[0][lane][w];
    #pragma unroll
    for (int ww = 1; ww < 8; ++ww) v += red[ww][lane][w];
    float r = fmaxf(v, 0.0f);
    if (branch)
        out_w[(size_t)lane * CD + c0 + w] = 1.0f / (1.0f + expf(-r));
    else
        out_mean[(size_t)lane * CD + c0 + w] = r;
}

// ---------------- Final combine: 4 float4/thread, per-wave seg search ----------------
// block = 256 threads covers 1024 float4 = 8 rows; grid = N*CV/1024
__global__ __launch_bounds__(256) void k_final(const float* __restrict__ x2,
                        const int* __restrict__ cum,
                        const float* __restrict__ out_mean,
                        const float* __restrict__ out_w,
                        float* __restrict__ out) {
    int t = threadIdx.x;
    int lane = t & 63;
    int w = t >> 6;
    size_t base = (size_t)blockIdx.x << 10;   // float4 index of block start
    int base_row = blockIdx.x << 3;
    // lane l searches the row used by element k=l of this wave; lanes >=4 harmless
    int row = base_row + 2 * lane + (w >> 1);
    int lo = 0, hi = NB - 1;
    while (lo < hi) {
        int mid = (lo + hi) >> 1;
        if (cum[mid] > row) hi = mid; else lo = mid + 1;
    }
    const float4* xv = (const float4*)x2;
    const float4* wv = (const float4*)out_w;
    const float4* mv = (const float4*)out_mean;
    float4* ov = (float4*)out;
    int colv = t & 127;
    // 4 independent x2 loads (ILP)
    float4 x0 = xv[base + t];
    float4 x1 = xv[base + 256 + t];
    float4 x2v = xv[base + 512 + t];
    float4 x3 = xv[base + 768 + t];
    float4 xs[4] = {x0, x1, x2v, x3};
    #pragma unroll
    for (int k = 0; k < 4; ++k) {
        int seg = __shfl(lo, k, 64);          // lane k searched row 2k+(w>>1)
        float4 x = xs[k];
        float4 ww = wv[(size_t)seg * CV + colv];
        float4 mm = mv[(size_t)seg * CV + colv];
        float4 o;
        o.x = x.x * (0.5f * ww.x + 0.75f) + mm.x;
        o.y = x.y * (0.5f * ww.y + 0.75f) + mm.y;
        o.z = x.z * (0.5f * ww.z + 0.75f) + mm.z;
        o.w = x.w * (0.5f * ww.w + 0.75f) + mm.w;
        ov[base + ((size_t)k << 8) + t] = o;
    }
}

extern "C" void kernel_launch(void* const* d_in, const int* in_sizes, int n_in,
                              void* d_out, int out_size, void* d_ws, size_t ws_size,
                              hipStream_t stream) {
    const float* x2  = (const float*)d_in[0];
    const int*   npt = (const int*)d_in[1];
    const float* W1a = (const float*)d_in[2];
    const float* g1a = (const float*)d_in[3];
    const float* b1a = (const float*)d_in[4];
    const float* W2a = (const float*)d_in[5];
    const float* W1b = (const float*)d_in[6];
    const float* g1b = (const float*)d_in[7];
    const float* b1b = (const float*)d_in[8];
    const float* W2b = (const float*)d_in[9];
    float* out = (float*)d_out;

    const int N   = in_sizes[0] / CD;      // 262144
    const int NC4 = (N * CD) / 4;          // total float4

    // scratch: big dead-before-final arrays live in d_out
    float* P      = out;                              // [NB*RS*CD]    = 4 MB
    float* mean_t = out + (size_t)NB * RS * CD;       // [CD*NB]       = 128 KB (transposed)
    float* h_t    = mean_t + (size_t)NB * CD;         // [2*MIDD*NB]   = 1 MB (transposed)
    // small live-at-final arrays in ws
    int*   cum      = (int*)d_ws;                     // 64 ints
    float* out_mean = (float*)d_ws + 64;              // [NB*CD]
    float* out_w    = out_mean + (size_t)NB * CD;     // [NB*CD]

    k_partial<<<NB * RS, 128, 0, stream>>>(x2, npt, P);
    k_mean<<<NB, 128, 0, stream>>>(P, npt, mean_t, cum);
    k_fc1<<<2 * (MIDD / 8), 512, 0, stream>>>(mean_t, W1a, g1a, b1a, W1b, g1b, b1b, h_t);
    k_fc2<<<2 * (CD / 8), 512, 0, stream>>>(h_t, W2a, W2b, out_mean, out_w);
    k_final<<<NC4 / 1024, 256, 0, stream>>>(x2, cum, out_mean, out_w, out);
}

// Round 4
// 363.613 us; speedup vs baseline: 2.0851x; 1.0293x over previous
//
#include <hip/hip_runtime.h>
#include <hip/hip_bf16.h>
#include <math.h>

#define NB    64          // number of segments (B)
#define CD    512         // channels C
#define CV    128         // C / 4 (float4 per row)
#define MIDD  2048        // 4*C
#define RS    64          // row-splits per segment in pass 1
#define EPSV  1e-5f
#define FPT   8           // float4 per thread in k_final

typedef float fx4 __attribute__((ext_vector_type(4)));   // native vector for nontemporal builtins

__device__ __forceinline__ float wave_sum64(float x) {
    #pragma unroll
    for (int o = 32; o; o >>= 1) x += __shfl_xor(x, o, 64);
    return x;
}

__device__ __forceinline__ int seg_search(const int* __restrict__ cum, int row) {
    int lo = 0, hi = NB - 1;
    while (lo < hi) {
        int mid = (lo + hi) >> 1;
        if (cum[mid] > row) hi = mid; else lo = mid + 1;
    }
    return lo;
}

// ---------------- Pass 1: per-segment partial sums ----------------
// grid = NB*RS blocks, 128 threads (thread = float4 column)
__global__ __launch_bounds__(128) void k_partial(const float* __restrict__ x2,
                          const int* __restrict__ npoint,
                          float* __restrict__ P) {
    int bx = blockIdx.x;
    int b  = bx >> 6;            // / RS
    int rs = bx & (RS - 1);
    int start = 0;
    for (int i = 0; i < b; ++i) start += npoint[i];
    int len   = npoint[b];
    int chunk = (len + RS - 1) / RS;
    int r0 = rs * chunk;
    int r1 = min(r0 + chunk, len);
    int t = threadIdx.x;
    const float4* xv = (const float4*)x2;
    float4 acc = make_float4(0.f, 0.f, 0.f, 0.f);
    #pragma unroll 8
    for (int r = r0; r < r1; ++r) {
        float4 v = xv[(size_t)(start + r) * CV + t];
        acc.x += v.x; acc.y += v.y; acc.z += v.z; acc.w += v.w;
    }
    ((float4*)P)[(size_t)bx * CV + t] = acc;
}

// ---------------- Pass 1b: reduce partials -> mean_t (transposed [C][NB]), cum ----------------
// grid = NB blocks, 128 threads
__global__ __launch_bounds__(128) void k_mean(const float* __restrict__ P,
                       const int* __restrict__ npoint,
                       float* __restrict__ mean_t,
                       int* __restrict__ cum) {
    int b = blockIdx.x;
    int t = threadIdx.x;
    const float4* Pv = (const float4*)P;
    float4 acc = make_float4(0.f, 0.f, 0.f, 0.f);
    #pragma unroll 8
    for (int rs = 0; rs < RS; ++rs) {
        float4 v = Pv[((size_t)(b * RS + rs)) * CV + t];
        acc.x += v.x; acc.y += v.y; acc.z += v.z; acc.w += v.w;
    }
    float inv = 1.0f / (float)npoint[b];
    int c = 4 * t;
    mean_t[(size_t)(c + 0) * NB + b] = acc.x * inv;
    mean_t[(size_t)(c + 1) * NB + b] = acc.y * inv;
    mean_t[(size_t)(c + 2) * NB + b] = acc.z * inv;
    mean_t[(size_t)(c + 3) * NB + b] = acc.w * inv;
    if (t == 0) {
        int s = 0;
        for (int i = 0; i <= b; ++i) s += npoint[i];
        cum[b] = s;
    }
}

// ---------------- FC1 + BN + ReLU (both branches), 8-way K-split ----------------
// grid = 2 * (MIDD/8) = 512 blocks, 512 threads (8 waves; lane = batch row)
__global__ __launch_bounds__(512) void k_fc1(const float* __restrict__ mean_t,
                                             const float* __restrict__ W1a,
                                             const float* __restrict__ g1a,
                                             const float* __restrict__ b1a,
                                             const float* __restrict__ W1b,
                                             const float* __restrict__ g1b,
                                             const float* __restrict__ b1b,
                                             float* __restrict__ h_t) {
    __shared__ float red[8][64][9];
    int bx = blockIdx.x;
    int branch = bx >> 8;            // 256 col-groups per branch
    int cg = bx & 255;
    int c0 = cg * 8;
    const float* W1 = branch ? W1b : W1a;
    const float* g  = branch ? g1b : g1a;
    const float* bb = branch ? b1b : b1a;
    int t = threadIdx.x;
    int lane = t & 63;               // batch row
    int w = t >> 6;                  // wave id = K-chunk = epilogue column
    float acc[8];
    #pragma unroll
    for (int i = 0; i < 8; ++i) acc[i] = 0.f;
    int k0 = w * 64;
    for (int k = k0; k < k0 + 64; ++k) {
        float mval = mean_t[(size_t)k * NB + lane];           // coalesced
        const float4* wr = (const float4*)(W1 + (size_t)k * MIDD + c0);
        float4 w0 = wr[0], w1 = wr[1];                        // broadcast
        acc[0] += mval * w0.x; acc[1] += mval * w0.y;
        acc[2] += mval * w0.z; acc[3] += mval * w0.w;
        acc[4] += mval * w1.x; acc[5] += mval * w1.y;
        acc[6] += mval * w1.z; acc[7] += mval * w1.w;
    }
    #pragma unroll
    for (int i = 0; i < 8; ++i) red[w][lane][i] = acc[i];
    __syncthreads();
    // epilogue: wave w owns column c0+w
    float v = red[0][lane][w];
    #pragma unroll
    for (int ww = 1; ww < 8; ++ww) v += red[ww][lane][w];
    float s = wave_sum64(v);
    float m = s * (1.0f / 64.0f);
    float d = v - m;
    float q = wave_sum64(d * d);
    float var = q * (1.0f / 64.0f);
    float val = fmaxf(d * rsqrtf(var + EPSV) * g[c0 + w] + bb[c0 + w], 0.0f);
    h_t[((size_t)branch * MIDD + c0 + w) * NB + lane] = val;  // coalesced
}

// ---------------- FC2 (+ReLU, +sigmoid for branch b), 8-way K-split ----------------
// grid = 2 * (CD/8) = 128 blocks, 512 threads
__global__ __launch_bounds__(512) void k_fc2(const float* __restrict__ h_t,
                                             const float* __restrict__ W2a,
                                             const float* __restrict__ W2b,
                                             float* __restrict__ out_mean,
                                             float* __restrict__ out_w) {
    __shared__ float red[8][64][9];
    int bx = blockIdx.x;
    int branch = bx >> 6;            // 64 col-groups per branch
    int cg = bx & 63;
    int c0 = cg * 8;
    const float* W2 = branch ? W2b : W2a;
    int t = threadIdx.x;
    int lane = t & 63;
    int w = t >> 6;
    float acc[8];
    #pragma unroll
    for (int i = 0; i < 8; ++i) acc[i] = 0.f;
    int k0 = w * 256;
    for (int k = k0; k < k0 + 256; ++k) {
        float hv = h_t[((size_t)branch * MIDD + k) * NB + lane];   // coalesced
        const float4* wr = (const float4*)(W2 + (size_t)k * CD + c0);
        float4 w0 = wr[0], w1 = wr[1];                             // broadcast
        acc[0] += hv * w0.x; acc[1] += hv * w0.y;
        acc[2] += hv * w0.z; acc[3] += hv * w0.w;
        acc[4] += hv * w1.x; acc[5] += hv * w1.y;
        acc[6] += hv * w1.z; acc[7] += hv * w1.w;
    }
    #pragma unroll
    for (int i = 0; i < 8; ++i) red[w][lane][i] = acc[i];
    __syncthreads();
    float v = red[0][lane][w];
    #pragma unroll
    for (int ww = 1; ww < 8; ++ww) v += red[ww][lane][w];
    float r = fmaxf(v, 0.0f);
    if (branch)
        out_w[(size_t)lane * CD + c0 + w] = 1.0f / (1.0f + expf(-r));
    else
        out_mean[(size_t)lane * CD + c0 + w] = r;
}

// ---------------- Final combine: 8 float4/thread, uniform-seg fast path ----------------
// block = 256 threads covers 2048 float4 = 16 rows; grid = N*CV/2048, REVERSED order
__global__ __launch_bounds__(256) void k_final(const float* __restrict__ x2,
                        const int* __restrict__ cum,
                        const float* __restrict__ out_mean,
                        const float* __restrict__ out_w,
                        float* __restrict__ out) {
    int t = threadIdx.x;
    int bx = (int)gridDim.x - 1 - (int)blockIdx.x;   // reversed: reuse x2 tail from L3
    size_t base = (size_t)bx << 11;                   // float4 index of block start
    int base_row = bx << 4;                           // 16 rows per block
    const fx4* xv = (const fx4*)x2;
    const fx4* wv = (const fx4*)out_w;
    const fx4* mv = (const fx4*)out_mean;
    fx4* ov = (fx4*)out;

    // issue all 8 x2 loads first (independent of the search)
    fx4 xs[FPT];
    #pragma unroll
    for (int k = 0; k < FPT; ++k)
        xs[k] = __builtin_nontemporal_load(&xv[base + ((size_t)k << 8) + t]);

    int seg_lo = seg_search(cum, base_row);
    int seg_hi = seg_search(cum, base_row + 15);
    int colv = t & 127;

    if (seg_lo == seg_hi) {          // block-uniform branch (common case)
        fx4 ww = wv[(size_t)seg_lo * CV + colv];
        fx4 mm = mv[(size_t)seg_lo * CV + colv];
        fx4 a = ww * 0.5f + 0.75f;
        #pragma unroll
        for (int k = 0; k < FPT; ++k) {
            fx4 o = xs[k] * a + mm;
            __builtin_nontemporal_store(o, &ov[base + ((size_t)k << 8) + t]);
        }
    } else {                          // rare: block straddles a segment boundary
        #pragma unroll
        for (int k = 0; k < FPT; ++k) {
            int row = base_row + ((k * 256 + t) >> 7);
            int seg = seg_search(cum, row);
            fx4 ww = wv[(size_t)seg * CV + colv];
            fx4 mm = mv[(size_t)seg * CV + colv];
            fx4 o = xs[k] * (ww * 0.5f + 0.75f) + mm;
            __builtin_nontemporal_store(o, &ov[base + ((size_t)k << 8) + t]);
        }
    }
}

extern "C" void kernel_launch(void* const* d_in, const int* in_sizes, int n_in,
                              void* d_out, int out_size, void* d_ws, size_t ws_size,
                              hipStream_t stream) {
    const float* x2  = (const float*)d_in[0];
    const int*   npt = (const int*)d_in[1];
    const float* W1a = (const float*)d_in[2];
    const float* g1a = (const float*)d_in[3];
    const float* b1a = (const float*)d_in[4];
    const float* W2a = (const float*)d_in[5];
    const float* W1b = (const float*)d_in[6];
    const float* g1b = (const float*)d_in[7];
    const float* b1b = (const float*)d_in[8];
    const float* W2b = (const float*)d_in[9];
    float* out = (float*)d_out;

    const int N   = in_sizes[0] / CD;      // 262144
    const int NC4 = (N * CD) / 4;          // total float4

    // scratch: big dead-before-final arrays live in d_out
    float* P      = out;                              // [NB*RS*CD]    = 8 MB
    float* mean_t = out + (size_t)NB * RS * CD;       // [CD*NB]       = 128 KB (transposed)
    float* h_t    = mean_t + (size_t)NB * CD;         // [2*MIDD*NB]   = 1 MB (transposed)
    // small live-at-final arrays in ws
    int*   cum      = (int*)d_ws;                     // 64 ints
    float* out_mean = (float*)d_ws + 64;              // [NB*CD]
    float* out_w    = out_mean + (size_t)NB * CD;     // [NB*CD]

    k_partial<<<NB * RS, 128, 0, stream>>>(x2, npt, P);
    k_mean<<<NB, 128, 0, stream>>>(P, npt, mean_t, cum);
    k_fc1<<<2 * (MIDD / 8), 512, 0, stream>>>(mean_t, W1a, g1a, b1a, W1b, g1b, b1b, h_t);
    k_fc2<<<2 * (CD / 8), 512, 0, stream>>>(h_t, W2a, W2b, out_mean, out_w);
    k_final<<<NC4 / (256 * FPT), 256, 0, stream>>>(x2, cum, out_mean, out_w, out);
}

// Round 5
// 362.053 us; speedup vs baseline: 2.0941x; 1.0043x over previous
//
#include <hip/hip_runtime.h>
#include <hip/hip_bf16.h>
#include <math.h>

#define NB    64          // number of segments (B)
#define CD    512         // channels C
#define CV    128         // C / 4 (float4 per row)
#define MIDD  2048        // 4*C
#define RS    64          // row-splits per segment in pass 1
#define EPSV  1e-5f
#define FPT   8           // float4 per thread in k_final

typedef float fx4 __attribute__((ext_vector_type(4)));   // native vector for nontemporal builtins

__device__ __forceinline__ float wave_sum64(float x) {
    #pragma unroll
    for (int o = 32; o; o >>= 1) x += __shfl_xor(x, o, 64);
    return x;
}

__device__ __forceinline__ int seg_search(const int* __restrict__ cum, int row) {
    int lo = 0, hi = NB - 1;
    while (lo < hi) {
        int mid = (lo + hi) >> 1;
        if (cum[mid] > row) hi = mid; else lo = mid + 1;
    }
    return lo;
}

// ---------------- Pass 1: per-segment partial sums (forward order) ----------------
// grid = NB*RS blocks, 128 threads (thread = float4 column)
__global__ __launch_bounds__(128) void k_partial(const float* __restrict__ x2,
                          const int* __restrict__ npoint,
                          float* __restrict__ P) {
    int bx = blockIdx.x;
    int b  = bx >> 6;            // / RS
    int rs = bx & (RS - 1);
    int start = 0;
    for (int i = 0; i < b; ++i) start += npoint[i];
    int len   = npoint[b];
    int chunk = (len + RS - 1) / RS;
    int r0 = rs * chunk;
    int r1 = min(r0 + chunk, len);
    int t = threadIdx.x;
    const float4* xv = (const float4*)x2;
    float4 acc = make_float4(0.f, 0.f, 0.f, 0.f);
    #pragma unroll 8
    for (int r = r0; r < r1; ++r) {
        float4 v = xv[(size_t)(start + r) * CV + t];
        acc.x += v.x; acc.y += v.y; acc.z += v.z; acc.w += v.w;
    }
    ((float4*)P)[(size_t)bx * CV + t] = acc;
}

// ---------------- Pass 1b: reduce partials -> mean_t (transposed [C][NB]), cum ----------------
// grid = NB blocks, 128 threads
__global__ __launch_bounds__(128) void k_mean(const float* __restrict__ P,
                       const int* __restrict__ npoint,
                       float* __restrict__ mean_t,
                       int* __restrict__ cum) {
    int b = blockIdx.x;
    int t = threadIdx.x;
    const float4* Pv = (const float4*)P;
    float4 acc = make_float4(0.f, 0.f, 0.f, 0.f);
    #pragma unroll 8
    for (int rs = 0; rs < RS; ++rs) {
        float4 v = Pv[((size_t)(b * RS + rs)) * CV + t];
        acc.x += v.x; acc.y += v.y; acc.z += v.z; acc.w += v.w;
    }
    float inv = 1.0f / (float)npoint[b];
    int c = 4 * t;
    mean_t[(size_t)(c + 0) * NB + b] = acc.x * inv;
    mean_t[(size_t)(c + 1) * NB + b] = acc.y * inv;
    mean_t[(size_t)(c + 2) * NB + b] = acc.z * inv;
    mean_t[(size_t)(c + 3) * NB + b] = acc.w * inv;
    if (t == 0) {
        int s = 0;
        for (int i = 0; i <= b; ++i) s += npoint[i];
        cum[b] = s;
    }
}

// ---------------- FC1 + BN + ReLU (both branches), 8-way K-split ----------------
// grid = 2 * (MIDD/8) = 512 blocks, 512 threads (8 waves; lane = batch row)
__global__ __launch_bounds__(512) void k_fc1(const float* __restrict__ mean_t,
                                             const float* __restrict__ W1a,
                                             const float* __restrict__ g1a,
                                             const float* __restrict__ b1a,
                                             const float* __restrict__ W1b,
                                             const float* __restrict__ g1b,
                                             const float* __restrict__ b1b,
                                             float* __restrict__ h_t) {
    __shared__ float red[8][64][9];
    int bx = blockIdx.x;
    int branch = bx >> 8;            // 256 col-groups per branch
    int cg = bx & 255;
    int c0 = cg * 8;
    const float* W1 = branch ? W1b : W1a;
    const float* g  = branch ? g1b : g1a;
    const float* bb = branch ? b1b : b1a;
    int t = threadIdx.x;
    int lane = t & 63;               // batch row
    int w = t >> 6;                  // wave id = K-chunk = epilogue column
    float acc[8];
    #pragma unroll
    for (int i = 0; i < 8; ++i) acc[i] = 0.f;
    int k0 = w * 64;
    for (int k = k0; k < k0 + 64; ++k) {
        float mval = mean_t[(size_t)k * NB + lane];           // coalesced
        const float4* wr = (const float4*)(W1 + (size_t)k * MIDD + c0);
        float4 w0 = wr[0], w1 = wr[1];                        // broadcast
        acc[0] += mval * w0.x; acc[1] += mval * w0.y;
        acc[2] += mval * w0.z; acc[3] += mval * w0.w;
        acc[4] += mval * w1.x; acc[5] += mval * w1.y;
        acc[6] += mval * w1.z; acc[7] += mval * w1.w;
    }
    #pragma unroll
    for (int i = 0; i < 8; ++i) red[w][lane][i] = acc[i];
    __syncthreads();
    // epilogue: wave w owns column c0+w
    float v = red[0][lane][w];
    #pragma unroll
    for (int ww = 1; ww < 8; ++ww) v += red[ww][lane][w];
    float s = wave_sum64(v);
    float m = s * (1.0f / 64.0f);
    float d = v - m;
    float q = wave_sum64(d * d);
    float var = q * (1.0f / 64.0f);
    float val = fmaxf(d * rsqrtf(var + EPSV) * g[c0 + w] + bb[c0 + w], 0.0f);
    h_t[((size_t)branch * MIDD + c0 + w) * NB + lane] = val;  // coalesced
}

// ---------------- FC2 (+ReLU, +sigmoid for branch b), 8-way K-split ----------------
// grid = 2 * (CD/8) = 128 blocks, 512 threads
__global__ __launch_bounds__(512) void k_fc2(const float* __restrict__ h_t,
                                             const float* __restrict__ W2a,
                                             const float* __restrict__ W2b,
                                             float* __restrict__ out_mean,
                                             float* __restrict__ out_w) {
    __shared__ float red[8][64][9];
    int bx = blockIdx.x;
    int branch = bx >> 6;            // 64 col-groups per branch
    int cg = bx & 63;
    int c0 = cg * 8;
    const float* W2 = branch ? W2b : W2a;
    int t = threadIdx.x;
    int lane = t & 63;
    int w = t >> 6;
    float acc[8];
    #pragma unroll
    for (int i = 0; i < 8; ++i) acc[i] = 0.f;
    int k0 = w * 256;
    for (int k = k0; k < k0 + 256; ++k) {
        float hv = h_t[((size_t)branch * MIDD + k) * NB + lane];   // coalesced
        const float4* wr = (const float4*)(W2 + (size_t)k * CD + c0);
        float4 w0 = wr[0], w1 = wr[1];                             // broadcast
        acc[0] += hv * w0.x; acc[1] += hv * w0.y;
        acc[2] += hv * w0.z; acc[3] += hv * w0.w;
        acc[4] += hv * w1.x; acc[5] += hv * w1.y;
        acc[6] += hv * w1.z; acc[7] += hv * w1.w;
    }
    #pragma unroll
    for (int i = 0; i < 8; ++i) red[w][lane][i] = acc[i];
    __syncthreads();
    float v = red[0][lane][w];
    #pragma unroll
    for (int ww = 1; ww < 8; ++ww) v += red[ww][lane][w];
    float r = fmaxf(v, 0.0f);
    if (branch)
        out_w[(size_t)lane * CD + c0 + w] = 1.0f / (1.0f + expf(-r));
    else
        out_mean[(size_t)lane * CD + c0 + w] = r;
}

// ---------------- Final combine: 8 float4/thread, uniform-seg fast path ----------------
// block = 256 threads covers 2048 float4 = 16 rows; grid = N*CV/2048, REVERSED order.
// x2 loads are NORMAL (must allocate in L3 so the next iteration's k_partial,
// reading forward, hits the head half); only the out stream is nontemporal.
__global__ __launch_bounds__(256) void k_final(const float* __restrict__ x2,
                        const int* __restrict__ cum,
                        const float* __restrict__ out_mean,
                        const float* __restrict__ out_w,
                        float* __restrict__ out) {
    int t = threadIdx.x;
    int bx = (int)gridDim.x - 1 - (int)blockIdx.x;   // reversed: reuse x2 tail from L3
    size_t base = (size_t)bx << 11;                   // float4 index of block start
    int base_row = bx << 4;                           // 16 rows per block
    const fx4* xv = (const fx4*)x2;
    const fx4* wv = (const fx4*)out_w;
    const fx4* mv = (const fx4*)out_mean;
    fx4* ov = (fx4*)out;

    // issue all 8 x2 loads first (independent of the search)
    fx4 xs[FPT];
    #pragma unroll
    for (int k = 0; k < FPT; ++k)
        xs[k] = xv[base + ((size_t)k << 8) + t];

    int seg_lo = seg_search(cum, base_row);
    int seg_hi = seg_search(cum, base_row + 15);
    int colv = t & 127;

    if (seg_lo == seg_hi) {          // block-uniform branch (common case)
        fx4 ww = wv[(size_t)seg_lo * CV + colv];
        fx4 mm = mv[(size_t)seg_lo * CV + colv];
        fx4 a = ww * 0.5f + 0.75f;
        #pragma unroll
        for (int k = 0; k < FPT; ++k) {
            fx4 o = xs[k] * a + mm;
            __builtin_nontemporal_store(o, &ov[base + ((size_t)k << 8) + t]);
        }
    } else {                          // rare: block straddles a segment boundary
        #pragma unroll
        for (int k = 0; k < FPT; ++k) {
            int row = base_row + ((k * 256 + t) >> 7);
            int seg = seg_search(cum, row);
            fx4 ww = wv[(size_t)seg * CV + colv];
            fx4 mm = mv[(size_t)seg * CV + colv];
            fx4 o = xs[k] * (ww * 0.5f + 0.75f) + mm;
            __builtin_nontemporal_store(o, &ov[base + ((size_t)k << 8) + t]);
        }
    }
}

extern "C" void kernel_launch(void* const* d_in, const int* in_sizes, int n_in,
                              void* d_out, int out_size, void* d_ws, size_t ws_size,
                              hipStream_t stream) {
    const float* x2  = (const float*)d_in[0];
    const int*   npt = (const int*)d_in[1];
    const float* W1a = (const float*)d_in[2];
    const float* g1a = (const float*)d_in[3];
    const float* b1a = (const float*)d_in[4];
    const float* W2a = (const float*)d_in[5];
    const float* W1b = (const float*)d_in[6];
    const float* g1b = (const float*)d_in[7];
    const float* b1b = (const float*)d_in[8];
    const float* W2b = (const float*)d_in[9];
    float* out = (float*)d_out;

    const int N   = in_sizes[0] / CD;      // 262144
    const int NC4 = (N * CD) / 4;          // total float4

    // scratch: big dead-before-final arrays live in d_out
    float* P      = out;                              // [NB*RS*CD]    = 8 MB
    float* mean_t = out + (size_t)NB * RS * CD;       // [CD*NB]       = 128 KB (transposed)
    float* h_t    = mean_t + (size_t)NB * CD;         // [2*MIDD*NB]   = 1 MB (transposed)
    // small live-at-final arrays in ws
    int*   cum      = (int*)d_ws;                     // 64 ints
    float* out_mean = (float*)d_ws + 64;              // [NB*CD]
    float* out_w    = out_mean + (size_t)NB * CD;     // [NB*CD]

    k_partial<<<NB * RS, 128, 0, stream>>>(x2, npt, P);
    k_mean<<<NB, 128, 0, stream>>>(P, npt, mean_t, cum);
    k_fc1<<<2 * (MIDD / 8), 512, 0, stream>>>(mean_t, W1a, g1a, b1a, W1b, g1b, b1b, h_t);
    k_fc2<<<2 * (CD / 8), 512, 0, stream>>>(h_t, W2a, W2b, out_mean, out_w);
    k_final<<<NC4 / (256 * FPT), 256, 0, stream>>>(x2, cum, out_mean, out_w, out);
}